// Round 10
// baseline (754.723 us; speedup 1.0000x reference)
//
#include <hip/hip_runtime.h>
#include <hip/hip_fp16.h>
#include <hip/hip_cooperative_groups.h>
#include <math.h>

namespace cg = cooperative_groups;

#define N4C 32768
#define N3C 65536
#define N2C 131072
#define N1C 262144

typedef _Float16 f16x8 __attribute__((ext_vector_type(8)));
typedef float f32x4 __attribute__((ext_vector_type(4)));
typedef float f32x16 __attribute__((ext_vector_type(16)));

__device__ __forceinline__ f32x4 mfma16(f16x8 a, f16x8 b, f32x4 c) {
  return __builtin_amdgcn_mfma_f32_16x16x32_f16(a, b, c, 0, 0, 0);
}
__device__ __forceinline__ f32x16 mfma32(f16x8 a, f16x8 b, f32x16 c) {
  return __builtin_amdgcn_mfma_f32_32x32x16_f16(a, b, c, 0, 0, 0);
}

__device__ __forceinline__ float celuf(float x) {
  return fmaxf(x, 0.f) + (__expf(fminf(x, 0.f)) - 1.f);
}

__device__ __forceinline__ float logsigf(float x) {
  float e = __expf(-fabsf(x));
  return fminf(x, 0.f) - __logf(1.f + e);
}

__device__ __forceinline__ float max3f(float a, float b, float c) {
  return fmaxf(fmaxf(a, b), c);
}

__device__ __forceinline__ _Float16 exp2_16(_Float16 x) {
  __half h; __builtin_memcpy(&h, &x, 2);
  h = hexp2(h);
  _Float16 r; __builtin_memcpy(&r, &h, 2);
  return r;
}

// celu(x) + 1; the -1 is folded into the post-MFMA bias.
__device__ __forceinline__ f16x8 celu8p1(f16x8 x) {
  f16x8 z = {};
  f16x8 mx = __builtin_elementwise_max(x, z);
  f16x8 mn = __builtin_elementwise_min(x, z) * (_Float16)1.44269504f;
#pragma unroll
  for (int i = 0; i < 8; ++i) mn[i] = exp2_16(mn[i]);
  return mx + mn;
}

// ---------------------------------------------------------------------------
// y4 = z @ W1a[:64] + b1a + pos4 @ W1a[64:67]  ([N4][64] f16)
// Fused tail blocks: vt3[p][k] = pos3[p] . W1a[64:67][k]  ([N3][64] f16)
// ---------------------------------------------------------------------------
__global__ __launch_bounds__(256) void y4_kernel(
    const float* __restrict__ z, const float* __restrict__ pos4,
    const float* __restrict__ pos3, const float* __restrict__ w1a,
    const float* __restrict__ b1a, _Float16* __restrict__ y4,
    _Float16* __restrict__ vt3) {
  if (blockIdx.x >= 512) {
    const int idx = (blockIdx.x - 512) * 256 + threadIdx.x;
    const int p = idx >> 3, seg = (idx & 7) * 8;
    const float q0 = pos3[p * 3 + 0];
    const float q1 = pos3[p * 3 + 1];
    const float q2 = pos3[p * 3 + 2];
    f16x8 v;
#pragma unroll
    for (int j = 0; j < 8; ++j) {
      const int k = seg + j;
      v[j] = (_Float16)(w1a[64 * 64 + k] * q0 + w1a[65 * 64 + k] * q1 +
                        w1a[66 * 64 + k] * q2);
    }
    *(f16x8*)(vt3 + (size_t)p * 64 + seg) = v;
    return;
  }
  const int lane = threadIdx.x & 63, wid = threadIdx.x >> 6;
  const int col = lane & 15, quad = lane >> 4;
  const int base = (blockIdx.x * 4 + wid) * 16;

  f16x8 Ba[2][4];
#pragma unroll
  for (int c = 0; c < 2; ++c)
#pragma unroll
    for (int t = 0; t < 4; ++t)
#pragma unroll
      for (int j = 0; j < 8; ++j)
        Ba[c][t][j] = (_Float16)w1a[(c * 32 + quad * 8 + j) * 64 + t * 16 + col];

  float wr[3][4];
#pragma unroll
  for (int c = 0; c < 3; ++c)
#pragma unroll
    for (int t = 0; t < 4; ++t)
      wr[c][t] = w1a[(64 + c) * 64 + t * 16 + col];

  float px[4], py[4], pz[4];
#pragma unroll
  for (int r = 0; r < 4; ++r) {
    const int row = base + quad * 4 + r;
    px[r] = pos4[row * 3 + 0];
    py[r] = pos4[row * 3 + 1];
    pz[r] = pos4[row * 3 + 2];
  }

  const float* zr = z + (size_t)(base + col) * 64;
  f16x8 A0, A1;
  {
    float4 f0 = *(const float4*)(zr + quad * 8);
    float4 f1 = *(const float4*)(zr + quad * 8 + 4);
    float4 f2 = *(const float4*)(zr + 32 + quad * 8);
    float4 f3 = *(const float4*)(zr + 32 + quad * 8 + 4);
    A0[0] = (_Float16)f0.x; A0[1] = (_Float16)f0.y; A0[2] = (_Float16)f0.z; A0[3] = (_Float16)f0.w;
    A0[4] = (_Float16)f1.x; A0[5] = (_Float16)f1.y; A0[6] = (_Float16)f1.z; A0[7] = (_Float16)f1.w;
    A1[0] = (_Float16)f2.x; A1[1] = (_Float16)f2.y; A1[2] = (_Float16)f2.z; A1[3] = (_Float16)f2.w;
    A1[4] = (_Float16)f3.x; A1[5] = (_Float16)f3.y; A1[6] = (_Float16)f3.z; A1[7] = (_Float16)f3.w;
  }
#pragma unroll
  for (int t = 0; t < 4; ++t) {
    f32x4 acc = {0.f, 0.f, 0.f, 0.f};
    acc = mfma16(A0, Ba[0][t], acc);
    acc = mfma16(A1, Ba[1][t], acc);
    const float bt = b1a[t * 16 + col];
#pragma unroll
    for (int r = 0; r < 4; ++r) {
      const float posterm =
          px[r] * wr[0][t] + py[r] * wr[1][t] + pz[r] * wr[2][t];
      y4[(size_t)(base + quad * 4 + r) * 64 + t * 16 + col] =
          (_Float16)(acc[r] + bt + posterm);
    }
  }
}

// ======================== standalone fallback kernels =======================
// (round-3 champion path, used if cooperative launch is unavailable)

__global__ __launch_bounds__(256) void l3_kernel(
    const _Float16* __restrict__ y4, const _Float16* __restrict__ vt3,
    const int* __restrict__ src3, const float* __restrict__ w1b,
    const float* __restrict__ b1b, _Float16* __restrict__ x3f) {
  const int lane = threadIdx.x & 63, wid = threadIdx.x >> 6;
  const int n = lane & 31;
  const int kh = lane >> 5;

  f16x8 Bb[4];
#pragma unroll
  for (int ks = 0; ks < 4; ++ks)
#pragma unroll
    for (int j = 0; j < 8; ++j)
      Bb[ks][j] = (_Float16)w1b[(ks * 16 + kh * 8 + j) * 32 + n];

  float s = 0.f;
#pragma unroll 4
  for (int k = 0; k < 32; ++k) s += w1b[(kh * 32 + k) * 32 + n];
  s += __shfl_xor(s, 32, 64);
  const float biasB = b1b[n] - s;

  const int gwave = blockIdx.x * 4 + wid;
  const int nw = gridDim.x << 2;

#pragma unroll 1
  for (int pb = gwave * 2; pb < N3C; pb += nw * 2) {
    const int s1 = src3[pb * 16 + n];
    const int p = pb + (n >> 4);
    const _Float16* yrow = y4 + (size_t)s1 * 64 + kh * 8;
    const _Float16* vrow = vt3 + (size_t)p * 64 + kh * 8;

    f16x8 A[4];
#pragma unroll
    for (int ks = 0; ks < 4; ++ks)
      A[ks] = *(const f16x8*)(yrow + ks * 16) - *(const f16x8*)(vrow + ks * 16);
#pragma unroll
    for (int ks = 0; ks < 4; ++ks) A[ks] = celu8p1(A[ks]);

    f32x16 acc = {};
#pragma unroll
    for (int ks = 0; ks < 4; ++ks) acc = mfma32(A[ks], Bb[ks], acc);

    float mA = fmaxf(max3f(max3f(acc[0], acc[1], acc[2]),
                           max3f(acc[3], acc[4], acc[5]), acc[6]), acc[7]);
    float mB = fmaxf(max3f(max3f(acc[8], acc[9], acc[10]),
                           max3f(acc[11], acc[12], acc[13]), acc[14]), acc[15]);
    mA = fmaxf(mA, __shfl_xor(mA, 32, 64));
    mB = fmaxf(mB, __shfl_xor(mB, 32, 64));

    const float mv = kh ? mB : mA;
    x3f[(size_t)(pb + kh) * 32 + n] = (_Float16)celuf(mv + biasB);
  }
}

__global__ __launch_bounds__(256) void y3_kernel(
    const _Float16* __restrict__ x3f, const float* __restrict__ pos3,
    const float* __restrict__ pos2, const float* __restrict__ w2a,
    const float* __restrict__ b2a, _Float16* __restrict__ y3,
    _Float16* __restrict__ vt2) {
  if (blockIdx.x >= 1024) {
    const int idx = (blockIdx.x - 1024) * 256 + threadIdx.x;
    const int p = idx >> 1, seg = (idx & 1) * 8;
    const float q0 = pos2[p * 3 + 0];
    const float q1 = pos2[p * 3 + 1];
    const float q2 = pos2[p * 3 + 2];
    f16x8 v;
#pragma unroll
    for (int j = 0; j < 8; ++j) {
      const int k = seg + j;
      v[j] = (_Float16)(w2a[32 * 16 + k] * q0 + w2a[33 * 16 + k] * q1 +
                        w2a[34 * 16 + k] * q2);
    }
    *(f16x8*)(vt2 + (size_t)p * 16 + seg) = v;
    return;
  }
  const int lane = threadIdx.x & 63, wid = threadIdx.x >> 6;
  const int col = lane & 15, quad = lane >> 4;
  const int base = (blockIdx.x * 4 + wid) * 16;

  f16x8 B;
#pragma unroll
  for (int j = 0; j < 8; ++j) B[j] = (_Float16)w2a[(quad * 8 + j) * 16 + col];

  float wr[3];
#pragma unroll
  for (int c = 0; c < 3; ++c) wr[c] = w2a[(32 + c) * 16 + col];

  float px[4], py[4], pz[4];
#pragma unroll
  for (int r = 0; r < 4; ++r) {
    const int row = base + quad * 4 + r;
    px[r] = pos3[row * 3 + 0];
    py[r] = pos3[row * 3 + 1];
    pz[r] = pos3[row * 3 + 2];
  }

  f16x8 A = *(const f16x8*)(x3f + (size_t)(base + col) * 32 + quad * 8);
  f32x4 d = {0.f, 0.f, 0.f, 0.f};
  d = mfma16(A, B, d);
  const float bt = b2a[col];
#pragma unroll
  for (int r = 0; r < 4; ++r) {
    const float posterm = px[r] * wr[0] + py[r] * wr[1] + pz[r] * wr[2];
    y3[(size_t)(base + quad * 4 + r) * 16 + col] =
        (_Float16)(d[r] + bt + posterm);
  }
}

__global__ __launch_bounds__(256) void y2_kernel(
    const _Float16* __restrict__ x2f, const float* __restrict__ pos2,
    const float* __restrict__ pos1, const float* __restrict__ w3a,
    const float* __restrict__ b3a, _Float16* __restrict__ y2,
    _Float16* __restrict__ vt1) {
  if (blockIdx.x >= 2048) {
    const int p = (blockIdx.x - 2048) * 256 + threadIdx.x;
    const float q0 = pos1[p * 3 + 0];
    const float q1 = pos1[p * 3 + 1];
    const float q2 = pos1[p * 3 + 2];
    f16x8 v;
#pragma unroll
    for (int k = 0; k < 8; ++k)
      v[k] = (_Float16)(w3a[16 * 8 + k] * q0 + w3a[17 * 8 + k] * q1 +
                        w3a[18 * 8 + k] * q2);
    *(f16x8*)(vt1 + (size_t)p * 8) = v;
    return;
  }
  const int lane = threadIdx.x & 63, wid = threadIdx.x >> 6;
  const int col = lane & 15, quad = lane >> 4;
  const int base = (blockIdx.x * 4 + wid) * 16;

  f16x8 B;
#pragma unroll
  for (int j = 0; j < 8; ++j) {
    int k = quad * 8 + j;
    B[j] = (k < 16 && col < 8) ? (_Float16)w3a[k * 8 + col] : (_Float16)0.f;
  }
  f16x8 A = *(const f16x8*)(x2f + (size_t)(base + col) * 16 + (quad & 1) * 8);
  f32x4 d = {0.f, 0.f, 0.f, 0.f};
  d = mfma16(A, B, d);
  if (col < 8) {
    float wr[3];
#pragma unroll
    for (int c = 0; c < 3; ++c) wr[c] = w3a[(16 + c) * 8 + col];
    const float bt = b3a[col];
#pragma unroll
    for (int r = 0; r < 4; ++r) {
      const int row = base + quad * 4 + r;
      const float posterm = pos2[row * 3 + 0] * wr[0] +
                            pos2[row * 3 + 1] * wr[1] +
                            pos2[row * 3 + 2] * wr[2];
      y2[(size_t)row * 8 + col] = (_Float16)(d[r] + bt + posterm);
    }
  }
}

__device__ __forceinline__ void l2_compute(
    int pr, f16x8 A_in, f16x8 vt, f16x8 Bb, float biasB, int kh, int n,
    _Float16* __restrict__ x2f) {
  f16x8 A = celu8p1(A_in - vt);
  f32x16 acc = {};
  acc = mfma32(A, Bb, acc);

  float mA = fmaxf(max3f(max3f(acc[0], acc[1], acc[2]),
                         max3f(acc[3], acc[4], acc[5]), acc[6]), acc[7]);
  float mB = fmaxf(max3f(max3f(acc[8], acc[9], acc[10]),
                         max3f(acc[11], acc[12], acc[13]), acc[14]), acc[15]);
  mA = fmaxf(mA, __shfl_xor(mA, 32, 64));
  mB = fmaxf(mB, __shfl_xor(mB, 32, 64));

  if (n < 16) {
    const float m = kh ? mB : mA;
    x2f[(size_t)(2 * pr + kh) * 16 + n] = (_Float16)celuf(m + biasB);
  }
}

__global__ __launch_bounds__(256) void l2_kernel(
    const _Float16* __restrict__ y3, const _Float16* __restrict__ vt2,
    const int* __restrict__ src2, const float* __restrict__ w2b,
    const float* __restrict__ b2b, _Float16* __restrict__ x2f) {
  const int lane = threadIdx.x & 63, wid = threadIdx.x >> 6;
  const int n = lane & 31;
  const int e = lane & 15;
  const int h = (lane >> 4) & 1;
  const int kh = lane >> 5;

  f16x8 Bb;
#pragma unroll
  for (int j = 0; j < 8; ++j)
    Bb[j] = (n < 16) ? (_Float16)w2b[(kh * 8 + j) * 16 + n] : (_Float16)0.f;
  float ws = 0.f;
#pragma unroll
  for (int k = 0; k < 16; ++k) ws += w2b[k * 16 + (n & 15)];
  const float biasB = b2b[n & 15] - ws;

  const int gwave = blockIdx.x * 4 + wid;
  const int nw = gridDim.x << 2;

#pragma unroll 1
  for (int pr = gwave; pr < N2C / 2; pr += 2 * nw) {
    const int pr2 = pr + nw;
    const int pa = 2 * pr + h, pb = 2 * pr2 + h;
    const int sa = src2[pa * 16 + e];
    const int sb = src2[pb * 16 + e];

    f16x8 Aa = *(const f16x8*)(y3 + (size_t)sa * 16 + kh * 8);
    f16x8 Ab = *(const f16x8*)(y3 + (size_t)sb * 16 + kh * 8);
    f16x8 va = *(const f16x8*)(vt2 + (size_t)pa * 16 + kh * 8);
    f16x8 vb = *(const f16x8*)(vt2 + (size_t)pb * 16 + kh * 8);

    l2_compute(pr,  Aa, va, Bb, biasB, kh, n, x2f);
    l2_compute(pr2, Ab, vb, Bb, biasB, kh, n, x2f);
  }
}

__device__ __forceinline__ void l1_compute(
    int pb, f16x8 A_in, f16x8 vt, f16x8 Bb, float biasB, float wl, float bl,
    int lane, float* __restrict__ out) {
  f16x8 A = celu8p1(A_in - vt);
  f32x16 acc = {};
  acc = mfma32(A, Bb, acc);

  float mA = fmaxf(max3f(max3f(acc[0], acc[1], acc[2]),
                         max3f(acc[3], acc[4], acc[5]), acc[6]), acc[7]);
  float mB = fmaxf(max3f(max3f(acc[8], acc[9], acc[10]),
                         max3f(acc[11], acc[12], acc[13]), acc[14]), acc[15]);
  mA = fmaxf(mA, __shfl_xor(mA, 32, 64));
  mB = fmaxf(mB, __shfl_xor(mB, 32, 64));

  float tA = celuf(mA + biasB) * wl;
  float tB = celuf(mB + biasB) * wl;
  tA += __shfl_xor(tA, 1, 64);
  tA += __shfl_xor(tA, 2, 64);
  tA += __shfl_xor(tA, 4, 64);
  tB += __shfl_xor(tB, 1, 64);
  tB += __shfl_xor(tB, 2, 64);
  tB += __shfl_xor(tB, 4, 64);
  if (lane == 0) {
    float2 o; o.x = logsigf(tA + bl); o.y = logsigf(tB + bl);
    *(float2*)(out + pb) = o;
  } else if (lane == 8) {
    float2 o; o.x = logsigf(tA + bl); o.y = logsigf(tB + bl);
    *(float2*)(out + pb + 2) = o;
  }
}

__global__ __launch_bounds__(256) void l1_kernel(
    const _Float16* __restrict__ y2, const _Float16* __restrict__ vt1,
    const int* __restrict__ src1, const float* __restrict__ w3b,
    const float* __restrict__ b3b, const float* __restrict__ wlin,
    const float* __restrict__ blin, float* __restrict__ out) {
  const int lane = threadIdx.x & 63, wid = threadIdx.x >> 6;
  const int m = lane & 31;
  const int kh = lane >> 5;
  const int g = 2 * kh + ((lane >> 4) & 1);

  f16x8 Bb;
  const int n = m;
#pragma unroll
  for (int j = 0; j < 8; ++j)
    Bb[j] = (n < 16 && (n >> 3) == kh) ? (_Float16)w3b[j * 8 + (n & 7)]
                                       : (_Float16)0.f;
  float ws = 0.f;
#pragma unroll
  for (int j = 0; j < 8; ++j) ws += w3b[j * 8 + (n & 7)];
  const float biasB = (n < 16) ? b3b[n & 7] - ws : 0.f;
  const float wl = (n < 16) ? wlin[n & 7] : 0.f;
  const float bl = blin[0];

  const int gwave = blockIdx.x * 4 + wid;
  const int nw = gridDim.x << 2;

#pragma unroll 1
  for (int q = gwave; q < N1C / 4; q += 2 * nw) {
    const int q2 = q + nw;
    const int pba = q * 4, pbb = q2 * 4;
    const int pa = pba + g, pb = pbb + g;
    const int sa = src1[q * 64 + lane];
    const int sb = src1[q2 * 64 + lane];

    f16x8 Aa = *(const f16x8*)(y2 + (size_t)sa * 8);
    f16x8 Ab = *(const f16x8*)(y2 + (size_t)sb * 8);
    f16x8 va = *(const f16x8*)(vt1 + (size_t)pa * 8);
    f16x8 vb = *(const f16x8*)(vt1 + (size_t)pb * 8);

    l1_compute(pba, Aa, va, Bb, biasB, wl, bl, lane, out);
    l1_compute(pbb, Ab, vb, Bb, biasB, wl, bl, lane, out);
  }
}

// ======================= fused cooperative kernel ===========================
// 1024 blocks x 256 threads, launch_bounds(256,4): needs only 4 blocks/CU
// co-resident (<=128 VGPR — 2x margin over the ~60-VGPR worst phase).
// Phases: l3 -> (y3 + vt2) -> l2 -> (y2 x2 + vt1) -> l1, grid.sync between.
// ---------------------------------------------------------------------------
struct FArgs {
  const _Float16* y4; const _Float16* vt3; const int* src3;
  const float* w1b; const float* b1b; _Float16* x3f;
  const float* pos3; const float* pos2; const float* w2a; const float* b2a;
  _Float16* y3; _Float16* vt2;
  const int* src2; const float* w2b; const float* b2b; _Float16* x2f;
  const float* pos1; const float* w3a; const float* b3a;
  _Float16* y2; _Float16* vt1;
  const int* src1; const float* w3b; const float* b3b;
  const float* wlin; const float* blin; float* out;
};

__global__ __launch_bounds__(256, 4) void fused_kernel(FArgs a) {
  const cg::grid_group grid = cg::this_grid();
  const int lane = threadIdx.x & 63, wid = threadIdx.x >> 6;
  const int blk = blockIdx.x;
  const int gwave = blk * 4 + wid;
  const int nw = gridDim.x << 2;  // 4096

  // ===== phase A: l3 =====
  {
    const int n = lane & 31;
    const int kh = lane >> 5;

    f16x8 Bb[4];
#pragma unroll
    for (int ks = 0; ks < 4; ++ks)
#pragma unroll
      for (int j = 0; j < 8; ++j)
        Bb[ks][j] = (_Float16)a.w1b[(ks * 16 + kh * 8 + j) * 32 + n];

    float s = 0.f;
#pragma unroll 4
    for (int k = 0; k < 32; ++k) s += a.w1b[(kh * 32 + k) * 32 + n];
    s += __shfl_xor(s, 32, 64);
    const float biasB = a.b1b[n] - s;

#pragma unroll 1
    for (int pb = gwave * 2; pb < N3C; pb += nw * 2) {
      const int s1 = a.src3[pb * 16 + n];
      const int p = pb + (n >> 4);
      const _Float16* yrow = a.y4 + (size_t)s1 * 64 + kh * 8;
      const _Float16* vrow = a.vt3 + (size_t)p * 64 + kh * 8;

      f16x8 A[4];
#pragma unroll
      for (int ks = 0; ks < 4; ++ks)
        A[ks] = *(const f16x8*)(yrow + ks * 16) - *(const f16x8*)(vrow + ks * 16);
#pragma unroll
      for (int ks = 0; ks < 4; ++ks) A[ks] = celu8p1(A[ks]);

      f32x16 acc = {};
#pragma unroll
      for (int ks = 0; ks < 4; ++ks) acc = mfma32(A[ks], Bb[ks], acc);

      float mA = fmaxf(max3f(max3f(acc[0], acc[1], acc[2]),
                             max3f(acc[3], acc[4], acc[5]), acc[6]), acc[7]);
      float mB = fmaxf(max3f(max3f(acc[8], acc[9], acc[10]),
                             max3f(acc[11], acc[12], acc[13]), acc[14]), acc[15]);
      mA = fmaxf(mA, __shfl_xor(mA, 32, 64));
      mB = fmaxf(mB, __shfl_xor(mB, 32, 64));

      const float mv = kh ? mB : mA;
      a.x3f[(size_t)(pb + kh) * 32 + n] = (_Float16)celuf(mv + biasB);
    }
  }
  grid.sync();

  // ===== phase B: y3 (all 1024 blocks, exact fit) + vt2 (all blocks) =====
  {
    const int col = lane & 15, quad = lane >> 4;
    const int base = gwave * 16;  // 1024 blk * 4 waves * 16 rows = 65536 = N3C

    f16x8 B;
#pragma unroll
    for (int j = 0; j < 8; ++j)
      B[j] = (_Float16)a.w2a[(quad * 8 + j) * 16 + col];

    float wr[3];
#pragma unroll
    for (int c = 0; c < 3; ++c) wr[c] = a.w2a[(32 + c) * 16 + col];

    float px[4], py[4], pz[4];
#pragma unroll
    for (int r = 0; r < 4; ++r) {
      const int row = base + quad * 4 + r;
      px[r] = a.pos3[row * 3 + 0];
      py[r] = a.pos3[row * 3 + 1];
      pz[r] = a.pos3[row * 3 + 2];
    }

    f16x8 A = *(const f16x8*)(a.x3f + (size_t)(base + col) * 32 + quad * 8);
    f32x4 d = {0.f, 0.f, 0.f, 0.f};
    d = mfma16(A, B, d);
    const float bt = a.b2a[col];
#pragma unroll
    for (int r = 0; r < 4; ++r) {
      const float posterm = px[r] * wr[0] + py[r] * wr[1] + pz[r] * wr[2];
      a.y3[(size_t)(base + quad * 4 + r) * 16 + col] =
          (_Float16)(d[r] + bt + posterm);
    }

    // vt2: 1024 blocks * 256 threads * 2 rows-per-2-threads = 131072 rows
    const int idx = blk * 256 + threadIdx.x;
    const int p = idx >> 1, seg = (idx & 1) * 8;
    const float q0 = a.pos2[p * 3 + 0];
    const float q1 = a.pos2[p * 3 + 1];
    const float q2 = a.pos2[p * 3 + 2];
    f16x8 v;
#pragma unroll
    for (int j = 0; j < 8; ++j) {
      const int k = seg + j;
      v[j] = (_Float16)(a.w2a[32 * 16 + k] * q0 + a.w2a[33 * 16 + k] * q1 +
                        a.w2a[34 * 16 + k] * q2);
    }
    *(f16x8*)(a.vt2 + (size_t)p * 16 + seg) = v;
  }
  grid.sync();

  // ===== phase C: l2 =====
  {
    const int n = lane & 31;
    const int e = lane & 15;
    const int h = (lane >> 4) & 1;
    const int kh = lane >> 5;

    f16x8 Bb;
#pragma unroll
    for (int j = 0; j < 8; ++j)
      Bb[j] = (n < 16) ? (_Float16)a.w2b[(kh * 8 + j) * 16 + n] : (_Float16)0.f;
    float ws = 0.f;
#pragma unroll
    for (int k = 0; k < 16; ++k) ws += a.w2b[k * 16 + (n & 15)];
    const float biasB = a.b2b[n & 15] - ws;

#pragma unroll 1
    for (int pr = gwave; pr < N2C / 2; pr += 2 * nw) {
      const int pr2 = pr + nw;
      const int pa = 2 * pr + h, pb = 2 * pr2 + h;
      const int sa = a.src2[pa * 16 + e];
      const int sb = a.src2[pb * 16 + e];

      f16x8 Aa = *(const f16x8*)(a.y3 + (size_t)sa * 16 + kh * 8);
      f16x8 Ab = *(const f16x8*)(a.y3 + (size_t)sb * 16 + kh * 8);
      f16x8 va = *(const f16x8*)(a.vt2 + (size_t)pa * 16 + kh * 8);
      f16x8 vb = *(const f16x8*)(a.vt2 + (size_t)pb * 16 + kh * 8);

      l2_compute(pr,  Aa, va, Bb, biasB, kh, n, a.x2f);
      l2_compute(pr2, Ab, vb, Bb, biasB, kh, n, a.x2f);
    }
  }
  grid.sync();

  // ===== phase D: y2 (2 passes of 1024 blocks) + vt1 (all blocks) =====
  {
    const int col = lane & 15, quad = lane >> 4;
#pragma unroll 1
    for (int b2 = blk; b2 < 2048; b2 += 1024) {
      const int base = (b2 * 4 + wid) * 16;

      f16x8 B;
#pragma unroll
      for (int j = 0; j < 8; ++j) {
        int k = quad * 8 + j;
        B[j] = (k < 16 && col < 8) ? (_Float16)a.w3a[k * 8 + col]
                                   : (_Float16)0.f;
      }
      f16x8 A =
          *(const f16x8*)(a.x2f + (size_t)(base + col) * 16 + (quad & 1) * 8);
      f32x4 d = {0.f, 0.f, 0.f, 0.f};
      d = mfma16(A, B, d);
      if (col < 8) {
        float wr[3];
#pragma unroll
        for (int c = 0; c < 3; ++c) wr[c] = a.w3a[(16 + c) * 8 + col];
        const float bt = a.b3a[col];
#pragma unroll
        for (int r = 0; r < 4; ++r) {
          const int row = base + quad * 4 + r;
          const float posterm = a.pos2[row * 3 + 0] * wr[0] +
                                a.pos2[row * 3 + 1] * wr[1] +
                                a.pos2[row * 3 + 2] * wr[2];
          a.y2[(size_t)row * 8 + col] = (_Float16)(d[r] + bt + posterm);
        }
      }
    }
    // vt1: 1024 blocks * 256 threads = 262144 = N1C rows
    const int p = blk * 256 + threadIdx.x;
    const float q0 = a.pos1[p * 3 + 0];
    const float q1 = a.pos1[p * 3 + 1];
    const float q2 = a.pos1[p * 3 + 2];
    f16x8 v;
#pragma unroll
    for (int k = 0; k < 8; ++k)
      v[k] = (_Float16)(a.w3a[16 * 8 + k] * q0 + a.w3a[17 * 8 + k] * q1 +
                        a.w3a[18 * 8 + k] * q2);
    *(f16x8*)(a.vt1 + (size_t)p * 8) = v;
  }
  grid.sync();

  // ===== phase E: l1 =====
  {
    const int m = lane & 31;
    const int kh = lane >> 5;
    const int g = 2 * kh + ((lane >> 4) & 1);

    f16x8 Bb;
    const int n = m;
#pragma unroll
    for (int j = 0; j < 8; ++j)
      Bb[j] = (n < 16 && (n >> 3) == kh) ? (_Float16)a.w3b[j * 8 + (n & 7)]
                                         : (_Float16)0.f;
    float ws = 0.f;
#pragma unroll
    for (int j = 0; j < 8; ++j) ws += a.w3b[j * 8 + (n & 7)];
    const float biasB = (n < 16) ? a.b3b[n & 7] - ws : 0.f;
    const float wl = (n < 16) ? a.wlin[n & 7] : 0.f;
    const float bl = a.blin[0];

#pragma unroll 1
    for (int q = gwave; q < N1C / 4; q += 2 * nw) {
      const int q2 = q + nw;
      const int pba = q * 4, pbb = q2 * 4;
      const int pa = pba + g, pb = pbb + g;
      const int sa = a.src1[q * 64 + lane];
      const int sb = a.src1[q2 * 64 + lane];

      f16x8 Aa = *(const f16x8*)(a.y2 + (size_t)sa * 8);
      f16x8 Ab = *(const f16x8*)(a.y2 + (size_t)sb * 8);
      f16x8 va = *(const f16x8*)(a.vt1 + (size_t)pa * 8);
      f16x8 vb = *(const f16x8*)(a.vt1 + (size_t)pb * 8);

      l1_compute(pba, Aa, va, Bb, biasB, wl, bl, lane, a.out);
      l1_compute(pbb, Ab, vb, Bb, biasB, wl, bl, lane, a.out);
    }
  }
}

extern "C" void kernel_launch(void* const* d_in, const int* in_sizes, int n_in,
                              void* d_out, int out_size, void* d_ws, size_t ws_size,
                              hipStream_t stream) {
  const float* z_mask = (const float*)d_in[0];
  const float* pos4 = (const float*)d_in[1];
  const float* pos3 = (const float*)d_in[2];
  const float* pos2 = (const float*)d_in[3];
  const float* pos1 = (const float*)d_in[4];
  const float* w1a = (const float*)d_in[9];
  const float* b1a = (const float*)d_in[10];
  const float* w1b = (const float*)d_in[11];
  const float* b1b = (const float*)d_in[12];
  const float* w2a = (const float*)d_in[13];
  const float* b2a = (const float*)d_in[14];
  const float* w2b = (const float*)d_in[15];
  const float* b2b = (const float*)d_in[16];
  const float* w3a = (const float*)d_in[17];
  const float* b3a = (const float*)d_in[18];
  const float* w3b = (const float*)d_in[19];
  const float* b3b = (const float*)d_in[20];
  const float* wlin = (const float*)d_in[21];
  const float* blin = (const float*)d_in[22];
  const int* src3 = (const int*)d_in[23];
  const int* src2 = (const int*)d_in[25];
  const int* src1 = (const int*)d_in[27];

  // ws (16 MB), lifetime-aliased (phase-synced; identical to round-3 layout):
  char* w = (char*)d_ws;
  _Float16* y4  = (_Float16*)(w);
  _Float16* vt3 = (_Float16*)(w + (4u << 20));
  _Float16* x3f = (_Float16*)(w + (12u << 20));
  _Float16* y3  = (_Float16*)(w);
  _Float16* vt2 = (_Float16*)(w + (4u << 20));
  _Float16* x2f = (_Float16*)(w + (8u << 20));
  _Float16* y2  = (_Float16*)(w + (2u << 20));
  _Float16* vt1 = (_Float16*)(w + (12u << 20));
  float* out = (float*)d_out;

  y4_kernel<<<2560, 256, 0, stream>>>(z_mask, pos4, pos3, w1a, b1a, y4, vt3);

  FArgs fa;
  fa.y4 = y4; fa.vt3 = vt3; fa.src3 = src3;
  fa.w1b = w1b; fa.b1b = b1b; fa.x3f = x3f;
  fa.pos3 = pos3; fa.pos2 = pos2; fa.w2a = w2a; fa.b2a = b2a;
  fa.y3 = y3; fa.vt2 = vt2;
  fa.src2 = src2; fa.w2b = w2b; fa.b2b = b2b; fa.x2f = x2f;
  fa.pos1 = pos1; fa.w3a = w3a; fa.b3a = b3a;
  fa.y2 = y2; fa.vt1 = vt1;
  fa.src1 = src1; fa.w3b = w3b; fa.b3b = b3b;
  fa.wlin = wlin; fa.blin = blin; fa.out = out;

  void* args[] = {&fa};
  hipError_t err = hipLaunchCooperativeKernel(
      (const void*)fused_kernel, dim3(1024), dim3(256), args, 0, stream);

  if (err != hipSuccess) {
    (void)hipGetLastError();  // clear sticky error; fall back to 5 launches
    l3_kernel<<<2048, 256, 0, stream>>>(y4, vt3, src3, w1b, b1b, x3f);
    y3_kernel<<<2048, 256, 0, stream>>>(x3f, pos3, pos2, w2a, b2a, y3, vt2);
    l2_kernel<<<2048, 256, 0, stream>>>(y3, vt2, src2, w2b, b2b, x2f);
    y2_kernel<<<3072, 256, 0, stream>>>(x2f, pos2, pos1, w3a, b3a, y2, vt1);
    l1_kernel<<<2048, 256, 0, stream>>>(y2, vt1, src1, w3b, b3b,
                                        wlin, blin, out);
  }
}

// Round 12
// 234.212 us; speedup vs baseline: 3.2224x; 3.2224x over previous
//
#include <hip/hip_runtime.h>
#include <hip/hip_fp16.h>
#include <math.h>

#define N4C 32768
#define N3C 65536
#define N2C 131072
#define N1C 262144

typedef _Float16 f16x8 __attribute__((ext_vector_type(8)));
typedef _Float16 f16x4 __attribute__((ext_vector_type(4)));
typedef float f32x4 __attribute__((ext_vector_type(4)));
typedef float f32x16 __attribute__((ext_vector_type(16)));

__device__ __forceinline__ f32x4 mfma16(f16x8 a, f16x8 b, f32x4 c) {
  return __builtin_amdgcn_mfma_f32_16x16x32_f16(a, b, c, 0, 0, 0);
}
__device__ __forceinline__ f32x16 mfma32(f16x8 a, f16x8 b, f32x16 c) {
  return __builtin_amdgcn_mfma_f32_32x32x16_f16(a, b, c, 0, 0, 0);
}

__device__ __forceinline__ float celuf(float x) {
  return fmaxf(x, 0.f) + (__expf(fminf(x, 0.f)) - 1.f);
}

__device__ __forceinline__ float logsigf(float x) {
  float e = __expf(-fabsf(x));
  return fminf(x, 0.f) - __logf(1.f + e);
}

__device__ __forceinline__ float max3f(float a, float b, float c) {
  return fmaxf(fmaxf(a, b), c);
}

__device__ __forceinline__ _Float16 exp2_16(_Float16 x) {
  __half h; __builtin_memcpy(&h, &x, 2);
  h = hexp2(h);
  _Float16 r; __builtin_memcpy(&r, &h, 2);
  return r;
}

// celu(x) + 1; the -1 is folded into the post-MFMA bias.
__device__ __forceinline__ f16x8 celu8p1(f16x8 x) {
  f16x8 z = {};
  f16x8 mx = __builtin_elementwise_max(x, z);
  f16x8 mn = __builtin_elementwise_min(x, z) * (_Float16)1.44269504f;
#pragma unroll
  for (int i = 0; i < 8; ++i) mn[i] = exp2_16(mn[i]);
  return mx + mn;
}

// ---------------------------------------------------------------------------
// y4 = z @ W1a[:64] + b1a + pos4 @ W1a[64:67]  ([N4][64] f16)
// Tail segments (independent, pos/weight-only): vt3, vt2, vt1 tables.
// Grid: 512 (gemm) + 2048 (vt3) + 1024 (vt2) + 1024 (vt1) = 4608 blocks.
// ---------------------------------------------------------------------------
__global__ __launch_bounds__(256) void y4_kernel(
    const float* __restrict__ z, const float* __restrict__ pos4,
    const float* __restrict__ pos3, const float* __restrict__ pos2,
    const float* __restrict__ pos1, const float* __restrict__ w1a,
    const float* __restrict__ w2a, const float* __restrict__ w3a,
    const float* __restrict__ b1a, _Float16* __restrict__ y4,
    _Float16* __restrict__ vt3, _Float16* __restrict__ vt2,
    _Float16* __restrict__ vt1) {
  const int bx = blockIdx.x;
  if (bx >= 3584) {  // vt1[p][k] = pos1[p] . W3a[16:19][k]  ([N1][8])
    const int p = (bx - 3584) * 256 + threadIdx.x;
    const float q0 = pos1[p * 3 + 0];
    const float q1 = pos1[p * 3 + 1];
    const float q2 = pos1[p * 3 + 2];
    f16x8 v;
#pragma unroll
    for (int k = 0; k < 8; ++k)
      v[k] = (_Float16)(w3a[16 * 8 + k] * q0 + w3a[17 * 8 + k] * q1 +
                        w3a[18 * 8 + k] * q2);
    *(f16x8*)(vt1 + (size_t)p * 8) = v;
    return;
  }
  if (bx >= 2560) {  // vt2[p][k] = pos2[p] . W2a[32:35][k]  ([N2][16])
    const int idx = (bx - 2560) * 256 + threadIdx.x;
    const int p = idx >> 1, seg = (idx & 1) * 8;
    const float q0 = pos2[p * 3 + 0];
    const float q1 = pos2[p * 3 + 1];
    const float q2 = pos2[p * 3 + 2];
    f16x8 v;
#pragma unroll
    for (int j = 0; j < 8; ++j) {
      const int k = seg + j;
      v[j] = (_Float16)(w2a[32 * 16 + k] * q0 + w2a[33 * 16 + k] * q1 +
                        w2a[34 * 16 + k] * q2);
    }
    *(f16x8*)(vt2 + (size_t)p * 16 + seg) = v;
    return;
  }
  if (bx >= 512) {  // vt3[p][k] = pos3[p] . W1a[64:67][k]  ([N3][64])
    const int idx = (bx - 512) * 256 + threadIdx.x;
    const int p = idx >> 3, seg = (idx & 7) * 8;
    const float q0 = pos3[p * 3 + 0];
    const float q1 = pos3[p * 3 + 1];
    const float q2 = pos3[p * 3 + 2];
    f16x8 v;
#pragma unroll
    for (int j = 0; j < 8; ++j) {
      const int k = seg + j;
      v[j] = (_Float16)(w1a[64 * 64 + k] * q0 + w1a[65 * 64 + k] * q1 +
                        w1a[66 * 64 + k] * q2);
    }
    *(f16x8*)(vt3 + (size_t)p * 64 + seg) = v;
    return;
  }
  const int lane = threadIdx.x & 63, wid = threadIdx.x >> 6;
  const int col = lane & 15, quad = lane >> 4;
  const int base = (bx * 4 + wid) * 16;

  f16x8 Ba[2][4];
#pragma unroll
  for (int c = 0; c < 2; ++c)
#pragma unroll
    for (int t = 0; t < 4; ++t)
#pragma unroll
      for (int j = 0; j < 8; ++j)
        Ba[c][t][j] = (_Float16)w1a[(c * 32 + quad * 8 + j) * 64 + t * 16 + col];

  float wr[3][4];
#pragma unroll
  for (int c = 0; c < 3; ++c)
#pragma unroll
    for (int t = 0; t < 4; ++t)
      wr[c][t] = w1a[(64 + c) * 64 + t * 16 + col];

  float px[4], py[4], pz[4];
#pragma unroll
  for (int r = 0; r < 4; ++r) {
    const int row = base + quad * 4 + r;
    px[r] = pos4[row * 3 + 0];
    py[r] = pos4[row * 3 + 1];
    pz[r] = pos4[row * 3 + 2];
  }

  const float* zr = z + (size_t)(base + col) * 64;
  f16x8 A0, A1;
  {
    float4 f0 = *(const float4*)(zr + quad * 8);
    float4 f1 = *(const float4*)(zr + quad * 8 + 4);
    float4 f2 = *(const float4*)(zr + 32 + quad * 8);
    float4 f3 = *(const float4*)(zr + 32 + quad * 8 + 4);
    A0[0] = (_Float16)f0.x; A0[1] = (_Float16)f0.y; A0[2] = (_Float16)f0.z; A0[3] = (_Float16)f0.w;
    A0[4] = (_Float16)f1.x; A0[5] = (_Float16)f1.y; A0[6] = (_Float16)f1.z; A0[7] = (_Float16)f1.w;
    A1[0] = (_Float16)f2.x; A1[1] = (_Float16)f2.y; A1[2] = (_Float16)f2.z; A1[3] = (_Float16)f2.w;
    A1[4] = (_Float16)f3.x; A1[5] = (_Float16)f3.y; A1[6] = (_Float16)f3.z; A1[7] = (_Float16)f3.w;
  }
#pragma unroll
  for (int t = 0; t < 4; ++t) {
    f32x4 acc = {0.f, 0.f, 0.f, 0.f};
    acc = mfma16(A0, Ba[0][t], acc);
    acc = mfma16(A1, Ba[1][t], acc);
    const float bt = b1a[t * 16 + col];
#pragma unroll
    for (int r = 0; r < 4; ++r) {
      const float posterm =
          px[r] * wr[0][t] + py[r] * wr[1][t] + pz[r] * wr[2][t];
      y4[(size_t)(base + quad * 4 + r) * 64 + t * 16 + col] =
          (_Float16)(acc[r] + bt + posterm);
    }
  }
}

// ---------------------------------------------------------------------------
// Fused-epilogue accumulators: one extra mfma16 per body folds the dense
// y-transform of THIS wave's freshly-computed x-row into acc (weights as
// A-operand rows=out-channel; x shuffled into B-operand cols=point-slot).
// ---------------------------------------------------------------------------
__device__ __forceinline__ void accum_y3(f32x4& acc3, f16x8 Af, float x,
                                         int colr, int quad, int i) {
  f16x8 Bf;
#pragma unroll
  for (int j = 0; j < 8; ++j) {
    const int sl = ((colr & 1) << 5) + quad * 8 + j;  // src lane = kh*32 + ch
    const float v = __shfl(x, sl, 64);
    Bf[j] = ((colr >> 1) == i) ? (_Float16)v : (_Float16)0.f;
  }
  acc3 = mfma16(Af, Bf, acc3);
}

__device__ __forceinline__ void accum_y2(f32x4& acc2, f16x8 Af, float x,
                                         int colr, int quad, int t) {
  f16x8 Bf;
#pragma unroll
  for (int j = 0; j < 8; ++j) {
    const int sl = ((colr & 1) << 5) + quad * 8 + j;  // valid only quad<2
    const float v = __shfl(x, sl, 64);
    Bf[j] = (quad < 2 && (colr >> 1) == t) ? (_Float16)v : (_Float16)0.f;
  }
  acc2 = mfma16(Af, Bf, acc2);
}

// ---------------------------------------------------------------------------
// Level 3 gather + FUSED y3: wave computes 8 points over 4 iterations; each
// body folds its 2 points into the y3 MFMA accumulator; finalize writes y3
// directly (x3f never materialized). GRID MUST BE 2048 (mapping baked).
// ---------------------------------------------------------------------------
__global__ __launch_bounds__(256) void l3_kernel(
    const _Float16* __restrict__ y4, const _Float16* __restrict__ vt3,
    const int* __restrict__ src3, const float* __restrict__ w1b,
    const float* __restrict__ b1b, const float* __restrict__ pos3,
    const float* __restrict__ w2a, const float* __restrict__ b2a,
    _Float16* __restrict__ y3) {
  const int lane = threadIdx.x & 63, wid = threadIdx.x >> 6;
  const int n = lane & 31;
  const int kh = lane >> 5;
  const int colr = lane & 15, quad = lane >> 4;

  f16x8 Bb[4];
#pragma unroll
  for (int ks = 0; ks < 4; ++ks)
#pragma unroll
    for (int j = 0; j < 8; ++j)
      Bb[ks][j] = (_Float16)w1b[(ks * 16 + kh * 8 + j) * 32 + n];

  float s = 0.f;
#pragma unroll 4
  for (int k = 0; k < 32; ++k) s += w1b[(kh * 32 + k) * 32 + n];
  s += __shfl_xor(s, 32, 64);
  const float biasB = b1b[n] - s;

  // epilogue A: rows=c(0..15), k=channel(0..31): Af[j] = w2a[k][c]
  f16x8 Af;
#pragma unroll
  for (int j = 0; j < 8; ++j)
    Af[j] = (_Float16)w2a[(quad * 8 + j) * 16 + colr];
  f32x4 acc3 = {0.f, 0.f, 0.f, 0.f};

  const int gwave = blockIdx.x * 4 + wid;
  const int nw = gridDim.x << 2;  // 8192

#pragma unroll 1
  for (int i = 0; i < 4; ++i) {
    const int pb = 2 * gwave + 2 * nw * i;
    const int s1 = src3[pb * 16 + n];
    const int p = pb + (n >> 4);
    const _Float16* yrow = y4 + (size_t)s1 * 64 + kh * 8;
    const _Float16* vrow = vt3 + (size_t)p * 64 + kh * 8;

    f16x8 A[4];
#pragma unroll
    for (int ks = 0; ks < 4; ++ks)
      A[ks] = *(const f16x8*)(yrow + ks * 16) - *(const f16x8*)(vrow + ks * 16);
#pragma unroll
    for (int ks = 0; ks < 4; ++ks) A[ks] = celu8p1(A[ks]);

    f32x16 acc = {};
#pragma unroll
    for (int ks = 0; ks < 4; ++ks) acc = mfma32(A[ks], Bb[ks], acc);

    float mA = fmaxf(max3f(max3f(acc[0], acc[1], acc[2]),
                           max3f(acc[3], acc[4], acc[5]), acc[6]), acc[7]);
    float mB = fmaxf(max3f(max3f(acc[8], acc[9], acc[10]),
                           max3f(acc[11], acc[12], acc[13]), acc[14]), acc[15]);
    mA = fmaxf(mA, __shfl_xor(mA, 32, 64));
    mB = fmaxf(mB, __shfl_xor(mB, 32, 64));

    // x3 value for this lane's (point pb+kh, channel n), f16-quantized
    const float x = (float)(_Float16)celuf((kh ? mB : mA) + biasB);
    accum_y3(acc3, Af, x, colr, quad, i);
  }

  // finalize: col = i*2+kh -> p = 2*gwave + 2*nw*(col>>1) + (col&1)
  if (colr < 8) {
    const int p = 2 * gwave + 2 * nw * (colr >> 1) + (colr & 1);
    const float q0 = pos3[p * 3 + 0];
    const float q1 = pos3[p * 3 + 1];
    const float q2 = pos3[p * 3 + 2];
    f16x4 o;
#pragma unroll
    for (int r = 0; r < 4; ++r) {
      const int c = quad * 4 + r;
      const float pt = q0 * w2a[32 * 16 + c] + q1 * w2a[33 * 16 + c] +
                       q2 * w2a[34 * 16 + c];
      o[r] = (_Float16)(acc3[r] + b2a[c] + pt);
    }
    *(f16x4*)(y3 + (size_t)p * 16 + quad * 4) = o;
  }
}

// ---------------------------------------------------------------------------
// Level 2 gather + FUSED y2: wave computes 16 points over 4 iterations;
// each body folds its point-pair into the y2 MFMA accumulator; finalize
// writes y2 directly (x2f never materialized). GRID MUST BE 2048.
// ---------------------------------------------------------------------------
__global__ __launch_bounds__(256) void l2_kernel(
    const _Float16* __restrict__ y3, const _Float16* __restrict__ vt2,
    const int* __restrict__ src2, const float* __restrict__ w2b,
    const float* __restrict__ b2b, const float* __restrict__ pos2,
    const float* __restrict__ w3a, const float* __restrict__ b3a,
    _Float16* __restrict__ y2) {
  const int lane = threadIdx.x & 63, wid = threadIdx.x >> 6;
  const int n = lane & 31;
  const int e = lane & 15;
  const int h = (lane >> 4) & 1;
  const int kh = lane >> 5;
  const int colr = lane & 15, quad = lane >> 4;

  f16x8 Bb;
#pragma unroll
  for (int j = 0; j < 8; ++j)
    Bb[j] = (n < 16) ? (_Float16)w2b[(kh * 8 + j) * 16 + n] : (_Float16)0.f;
  float ws = 0.f;
#pragma unroll
  for (int k = 0; k < 16; ++k) ws += w2b[k * 16 + (n & 15)];
  const float biasB = b2b[n & 15] - ws;

  // epilogue A: rows=c(0..7), k=channel(0..15); zero elsewhere
  f16x8 Af = {};
#pragma unroll
  for (int j = 0; j < 8; ++j) {
    const int k = quad * 8 + j;
    Af[j] = (k < 16 && colr < 8) ? (_Float16)w3a[k * 8 + colr] : (_Float16)0.f;
  }
  f32x4 acc2 = {0.f, 0.f, 0.f, 0.f};

  const int gwave = blockIdx.x * 4 + wid;
  const int nw = gridDim.x << 2;  // 8192

#pragma unroll 1
  for (int i = 0; i < 4; ++i) {
    const int pr = gwave + 2 * nw * i;
    const int pr2 = pr + nw;
    const int pa = 2 * pr + h, pb = 2 * pr2 + h;
    const int sa = src2[pa * 16 + e];
    const int sb = src2[pb * 16 + e];

    f16x8 Aa = *(const f16x8*)(y3 + (size_t)sa * 16 + kh * 8);
    f16x8 Ab = *(const f16x8*)(y3 + (size_t)sb * 16 + kh * 8);
    f16x8 va = *(const f16x8*)(vt2 + (size_t)pa * 16 + kh * 8);
    f16x8 vb = *(const f16x8*)(vt2 + (size_t)pb * 16 + kh * 8);

#pragma unroll
    for (int sub = 0; sub < 2; ++sub) {
      const f16x8 A = celu8p1((sub ? Ab : Aa) - (sub ? vb : va));
      f32x16 acc = {};
      acc = mfma32(A, Bb, acc);

      float mA = fmaxf(max3f(max3f(acc[0], acc[1], acc[2]),
                             max3f(acc[3], acc[4], acc[5]), acc[6]), acc[7]);
      float mB = fmaxf(max3f(max3f(acc[8], acc[9], acc[10]),
                             max3f(acc[11], acc[12], acc[13]), acc[14]),
                       acc[15]);
      mA = fmaxf(mA, __shfl_xor(mA, 32, 64));
      mB = fmaxf(mB, __shfl_xor(mB, 32, 64));

      // x2 value: lanes n<16 (both kh halves) hold channel n of point
      // 2*pr(+nw*sub)+kh, f16-quantized
      const float x = (float)(_Float16)celuf((kh ? mB : mA) + biasB);
      accum_y2(acc2, Af, x, colr, quad, 2 * i + sub);
    }
  }

  // finalize: col = t*2+kh, t = it*2+sub -> pr = gwave + 2*nw*it + nw*sub
  if (quad < 2) {
    const int t = colr >> 1, kh2 = colr & 1;
    const int it = t >> 1, sub = t & 1;
    const int pr = gwave + 2 * nw * it + nw * sub;
    const int p = 2 * pr + kh2;
    const float q0 = pos2[p * 3 + 0];
    const float q1 = pos2[p * 3 + 1];
    const float q2 = pos2[p * 3 + 2];
    f16x4 o;
#pragma unroll
    for (int r = 0; r < 4; ++r) {
      const int c = quad * 4 + r;
      const float pt = q0 * w3a[16 * 8 + c] + q1 * w3a[17 * 8 + c] +
                       q2 * w3a[18 * 8 + c];
      o[r] = (_Float16)(acc2[r] + b3a[c] + pt);
    }
    *(f16x4*)(y2 + (size_t)p * 8 + quad * 4) = o;
  }
}

// ---------------------------------------------------------------------------
// Level 1 gather, pair-pipelined: 4 points/wave via block-diag mfma_32x32x16,
// vtab position fold. (unchanged champion)
// ---------------------------------------------------------------------------
__device__ __forceinline__ void l1_compute(
    int pb, f16x8 A_in, f16x8 vt, f16x8 Bb, float biasB, float wl, float bl,
    int lane, float* __restrict__ out) {
  f16x8 A = celu8p1(A_in - vt);
  f32x16 acc = {};
  acc = mfma32(A, Bb, acc);

  float mA = fmaxf(max3f(max3f(acc[0], acc[1], acc[2]),
                         max3f(acc[3], acc[4], acc[5]), acc[6]), acc[7]);
  float mB = fmaxf(max3f(max3f(acc[8], acc[9], acc[10]),
                         max3f(acc[11], acc[12], acc[13]), acc[14]), acc[15]);
  mA = fmaxf(mA, __shfl_xor(mA, 32, 64));
  mB = fmaxf(mB, __shfl_xor(mB, 32, 64));

  float tA = celuf(mA + biasB) * wl;  // wl==0 for n>=16
  float tB = celuf(mB + biasB) * wl;
  tA += __shfl_xor(tA, 1, 64);
  tA += __shfl_xor(tA, 2, 64);
  tA += __shfl_xor(tA, 4, 64);
  tB += __shfl_xor(tB, 1, 64);
  tB += __shfl_xor(tB, 2, 64);
  tB += __shfl_xor(tB, 4, 64);
  if (lane == 0) {
    float2 o; o.x = logsigf(tA + bl); o.y = logsigf(tB + bl);
    *(float2*)(out + pb) = o;
  } else if (lane == 8) {
    float2 o; o.x = logsigf(tA + bl); o.y = logsigf(tB + bl);
    *(float2*)(out + pb + 2) = o;
  }
}

__global__ __launch_bounds__(256) void l1_kernel(
    const _Float16* __restrict__ y2, const _Float16* __restrict__ vt1,
    const int* __restrict__ src1, const float* __restrict__ w3b,
    const float* __restrict__ b3b, const float* __restrict__ wlin,
    const float* __restrict__ blin, float* __restrict__ out) {
  const int lane = threadIdx.x & 63, wid = threadIdx.x >> 6;
  const int m = lane & 31;
  const int kh = lane >> 5;
  const int g = 2 * kh + ((lane >> 4) & 1);

  f16x8 Bb;
  const int n = m;
#pragma unroll
  for (int j = 0; j < 8; ++j)
    Bb[j] = (n < 16 && (n >> 3) == kh) ? (_Float16)w3b[j * 8 + (n & 7)]
                                       : (_Float16)0.f;
  float ws = 0.f;
#pragma unroll
  for (int j = 0; j < 8; ++j) ws += w3b[j * 8 + (n & 7)];
  const float biasB = (n < 16) ? b3b[n & 7] - ws : 0.f;
  const float wl = (n < 16) ? wlin[n & 7] : 0.f;
  const float bl = blin[0];

  const int gwave = blockIdx.x * 4 + wid;
  const int nw = gridDim.x << 2;

#pragma unroll 1
  for (int q = gwave; q < N1C / 4; q += 2 * nw) {
    const int q2 = q + nw;
    const int pba = q * 4, pbb = q2 * 4;
    const int pa = pba + g, pb = pbb + g;
    const int sa = src1[q * 64 + lane];
    const int sb = src1[q2 * 64 + lane];

    f16x8 Aa = *(const f16x8*)(y2 + (size_t)sa * 8);
    f16x8 Ab = *(const f16x8*)(y2 + (size_t)sb * 8);
    f16x8 va = *(const f16x8*)(vt1 + (size_t)pa * 8);
    f16x8 vb = *(const f16x8*)(vt1 + (size_t)pb * 8);

    l1_compute(pba, Aa, va, Bb, biasB, wl, bl, lane, out);
    l1_compute(pbb, Ab, vb, Bb, biasB, wl, bl, lane, out);
  }
}

extern "C" void kernel_launch(void* const* d_in, const int* in_sizes, int n_in,
                              void* d_out, int out_size, void* d_ws, size_t ws_size,
                              hipStream_t stream) {
  const float* z_mask = (const float*)d_in[0];
  const float* pos4 = (const float*)d_in[1];
  const float* pos3 = (const float*)d_in[2];
  const float* pos2 = (const float*)d_in[3];
  const float* pos1 = (const float*)d_in[4];
  const float* w1a = (const float*)d_in[9];
  const float* b1a = (const float*)d_in[10];
  const float* w1b = (const float*)d_in[11];
  const float* b1b = (const float*)d_in[12];
  const float* w2a = (const float*)d_in[13];
  const float* b2a = (const float*)d_in[14];
  const float* w2b = (const float*)d_in[15];
  const float* b2b = (const float*)d_in[16];
  const float* w3a = (const float*)d_in[17];
  const float* b3a = (const float*)d_in[18];
  const float* w3b = (const float*)d_in[19];
  const float* b3b = (const float*)d_in[20];
  const float* wlin = (const float*)d_in[21];
  const float* blin = (const float*)d_in[22];
  const int* src3 = (const int*)d_in[23];
  const int* src2 = (const int*)d_in[25];
  const int* src1 = (const int*)d_in[27];

  // ws (24 MB used; harness poison-fill shows ws is 256 MB), alias-free:
  //   y4  [0,4M)  | vt3 [4M,12M) | y3 [12M,14M) | y2 [14M,16M)
  //   vt2 [16M,20M) | vt1 [20M,24M)
  char* w = (char*)d_ws;
  _Float16* y4  = (_Float16*)(w);
  _Float16* vt3 = (_Float16*)(w + (4u << 20));
  _Float16* y3  = (_Float16*)(w + (12u << 20));
  _Float16* y2  = (_Float16*)(w + (14u << 20));
  _Float16* vt2 = (_Float16*)(w + (16u << 20));
  _Float16* vt1 = (_Float16*)(w + (20u << 20));
  float* out = (float*)d_out;

  y4_kernel<<<4608, 256, 0, stream>>>(z_mask, pos4, pos3, pos2, pos1, w1a,
                                      w2a, w3a, b1a, y4, vt3, vt2, vt1);
  l3_kernel<<<2048, 256, 0, stream>>>(y4, vt3, src3, w1b, b1b, pos3, w2a,
                                      b2a, y3);  // grid baked: 2048
  l2_kernel<<<2048, 256, 0, stream>>>(y3, vt2, src2, w2b, b2b, pos2, w3a,
                                      b3a, y2);  // grid baked: 2048
  l1_kernel<<<2048, 256, 0, stream>>>(y2, vt1, src1, w3b, b3b,
                                      wlin, blin, out);
}